// Round 5
// baseline (320.542 us; speedup 1.0000x reference)
//
#include <hip/hip_runtime.h>
#include <hip/hip_bf16.h>

#define BSZ 4096
#define MAXLEN 200
#define EDIM 112

#define TBL_GROUPS 1400014          // (100001*112)/8 groups incl. 14 zero groups
#define TBL_ZGROUPS 14
#define AFRAG_JOBS (256 * 128 * 64) // M16 x k32 x lane

typedef __attribute__((ext_vector_type(8))) short bf16x8;
typedef __attribute__((ext_vector_type(4))) float f32x4;

// f32 -> bf16 (RNE), bit-level
static __device__ __forceinline__ short f2bf(float f) {
    unsigned u = __float_as_uint(f);
    unsigned r = (u + 0x7fffu + ((u >> 16) & 1u)) >> 16;
    return (short)r;
}
static __device__ __forceinline__ float bf2f(short s) {
    return __uint_as_float(((unsigned)(unsigned short)s) << 16);
}
static __device__ __forceinline__ bf16x8 cvt8(float4 a, float4 b) {
    bf16x8 r;
    r[0] = f2bf(a.x); r[1] = f2bf(a.y); r[2] = f2bf(a.z); r[3] = f2bf(a.w);
    r[4] = f2bf(b.x); r[5] = f2bf(b.y); r[6] = f2bf(b.z); r[7] = f2bf(b.w);
    return r;
}
static __device__ __forceinline__ unsigned pack2(float a, float b) {
    return ((unsigned)f2bf(a) & 0xffffu) | ((unsigned)f2bf(b) << 16);
}

// async global->LDS, 16 B per lane: global src per-lane, LDS dest uniform+lane*16.
static __device__ __forceinline__ void glds16(const unsigned short* g, unsigned short* l) {
    __builtin_amdgcn_global_load_lds(
        (__attribute__((address_space(1))) void*)(void*)g,
        (__attribute__((address_space(3))) void*)l, 16, 0, 0);
}

// Combined prep stream: [0, TBL_GROUPS) = table f32->bf16 (PAD zero rows);
// [TBL_GROUPS, +AFRAG_JOBS) = A (f32 [4096x4096]) -> bf16 MFMA fragments Asw.
__global__ __launch_bounds__(256) void prep(const float* __restrict__ emb,
                                            unsigned short* __restrict__ Ebf,
                                            const float* __restrict__ Af,
                                            unsigned short* __restrict__ Asw) {
    int g = blockIdx.x * 256 + threadIdx.x;
    if (g < TBL_GROUPS) {
        bf16x8 o;
        if (g < TBL_ZGROUPS) {
            #pragma unroll
            for (int i = 0; i < 8; ++i) o[i] = 0;
        } else {
            const float* p = emb + (size_t)(g - TBL_ZGROUPS) * 8;
            float4 a = *(const float4*)p;
            float4 b = *(const float4*)(p + 4);
            o = cvt8(a, b);
        }
        *(bf16x8*)(Ebf + (size_t)g * 8) = o;
    } else {
        int g2 = g - TBL_GROUPS;
        if (g2 >= AFRAG_JOBS) return;
        int lane = g2 & 63;
        int k32 = (g2 >> 6) & 127;
        int M16 = g2 >> 13;
        int nrow = lane & 15, quad = lane >> 4;
        const float* p = Af + (size_t)(M16 * 16 + nrow) * BSZ + k32 * 32 + quad * 8;
        float4 a0 = *(const float4*)p;
        float4 a1 = *(const float4*)(p + 4);
        *(bf16x8*)(Asw + (((size_t)M16 * 128 + k32) * 64 + lane) * 8) = cvt8(a0, a1);
    }
}

// bf16-table gather+mean-pool. One block per session; 4 waves x 4 rows/wave,
// 16 B/lane loads; Ebf row 0 is zeros (PAD).  Writes S and inits acc.
__global__ __launch_bounds__(256) void gather_pool_bf(const unsigned short* __restrict__ Ebf,
                                                      const int* __restrict__ items,
                                                      const float* __restrict__ slen,
                                                      float* __restrict__ S,
                                                      float* __restrict__ acc) {
    __shared__ float part[16][14][8];
    int wave = threadIdx.x >> 6;
    int lane = threadIdx.x & 63;
    int b = blockIdx.x;
    int rg = lane / 14;   // 0..3 for lanes 0..55
    int c  = lane % 14;
    const int* it = items + (size_t)b * MAXLEN + wave * 50;
    float a[8];
    #pragma unroll
    for (int e = 0; e < 8; ++e) a[e] = 0.f;
    if (lane < 56) {
        #pragma unroll
        for (int t = 0; t < 13; ++t) {
            int j = t * 4 + rg;
            int idx = 0;
            if (j < 50) idx = it[j];               // idx==0 -> zero row (PAD)
            bf16x8 v = *(const bf16x8*)(Ebf + (size_t)idx * EDIM + c * 8);
            #pragma unroll
            for (int e = 0; e < 8; ++e) a[e] += bf2f(v[e]);
        }
        #pragma unroll
        for (int e = 0; e < 8; ++e) part[wave * 4 + rg][c][e] = a[e];
    }
    __syncthreads();
    int tid = threadIdx.x;
    if (tid < EDIM) {
        int cc = tid >> 3, ee = tid & 7;
        float s = 0.f;
        #pragma unroll
        for (int g = 0; g < 16; ++g) s += part[g][cc][ee];
        s /= slen[b];
        S[(size_t)b * EDIM + tid]   = s;
        acc[(size_t)b * EDIM + tid] = s;
    }
}

// Load 8 consecutive f32 (if valid) -> bf16x8 fragment.
static __device__ __forceinline__ bf16x8 ldcvt(const float* p, bool valid) {
    if (valid) {
        float4 a = *(const float4*)(p);
        float4 b = *(const float4*)(p + 4);
        return cvt8(a, b);
    }
    bf16x8 z;
    #pragma unroll
    for (int i = 0; i < 8; ++i) z[i] = 0;
    return z;
}

// Layer-0 only: T1 = S @ W0^T -> Bsw fragment layout.  One wave per 16
// sessions, grid 256.
__global__ __launch_bounds__(64, 4) void fused_mid0(const float* __restrict__ Sin,
                                                    const float* __restrict__ W,
                                                    unsigned short* __restrict__ Bsw) {
    __shared__ unsigned short Ylds[16][136];  // bank-skewed rows
    int lane = threadIdx.x;
    int gw = blockIdx.x;          // 0..255
    int j0 = gw * 16;
    int nrow = lane & 15;
    int quad = lane >> 4;
    int ses = j0 + nrow;

    float4 v[7];
    const float4* p = (const float4*)(Sin + (size_t)ses * EDIM + quad * 28);
    #pragma unroll
    for (int i = 0; i < 7; ++i) v[i] = p[i];

    #pragma unroll
    for (int i = 0; i < 7; ++i) {
        uint2 pk;
        pk.x = pack2(v[i].x, v[i].y);
        pk.y = pack2(v[i].z, v[i].w);
        *(uint2*)&Ylds[nrow][quad * 28 + i * 4] = pk;
    }
    *(uint2*)&Ylds[nrow][112 + quad * 4] = make_uint2(0u, 0u);
    __syncthreads();

    bf16x8 aF[4];
    #pragma unroll
    for (int k32 = 0; k32 < 4; ++k32)
        aF[k32] = *(bf16x8*)&Ylds[nrow][k32 * 32 + quad * 8];

    f32x4 acc[7];
    #pragma unroll
    for (int t = 0; t < 7; ++t) acc[t] = (f32x4){0.f, 0.f, 0.f, 0.f};
    #pragma unroll
    for (int t = 0; t < 7; ++t) {
        const float* wr = W + (size_t)(16 * t + nrow) * EDIM;
        #pragma unroll
        for (int k32 = 0; k32 < 4; ++k32) {
            bf16x8 bF = ldcvt(wr + k32 * 32 + quad * 8, (k32 < 3) || (quad < 2));
            acc[t] = __builtin_amdgcn_mfma_f32_16x16x32_bf16(aF[k32], bF, acc[t], 0, 0, 0);
        }
    }

    int k32f = j0 >> 5;
    int qp = ((j0 >> 4) & 1) * 2 + (quad >> 1);
    int e0 = (quad & 1) * 4;
    #pragma unroll
    for (int t = 0; t < 7; ++t) {
        uint2 pk;
        pk.x = pack2(acc[t][0], acc[t][1]);
        pk.y = pack2(acc[t][2], acc[t][3]);
        *(uint2*)(Bsw + ((size_t)(k32f * 7 + t) * 64 + qp * 16 + nrow) * 8 + e0) = pk;
    }
}

// Whole-layer kernel, NO K-split: grid 256 blocks x 512 thr; block owns rows
// [16m, 16m+16) over the FULL K=4096.  Wave t<7 owns output cols [16t,16t+16)
// (one 16x16 C-frag = 4 VGPRs); wave 7 stages A.  Per k32-pair stage: 8 waves
// x 2 glds16 (wave7 -> A frags, wave t -> B frag t) = 16 KB, 4 LDS buffers,
// 3-deep prefetch, counted s_waitcnt vmcnt(4) + raw s_barrier (never drain in
// loop).  Epilogue fully in-block (rows are exclusive): D-scale, row-norm
// (4 shfl_xor + tiny LDS), acc/out update, and T' = Y @ W^T -> BswOut.
template <int LAST>
__global__ __launch_bounds__(512, 1) void bg_layer(const unsigned short* __restrict__ Asw,
                                                   const unsigned short* __restrict__ Bsw,
                                                   const float* __restrict__ Dm,
                                                   float* __restrict__ accb,
                                                   const float* __restrict__ W,
                                                   unsigned short* __restrict__ BswOut,
                                                   float* __restrict__ out) {
    __shared__ unsigned short Abuf[4][2][512];      // 8 KB
    __shared__ unsigned short Bbuf[4][2][7][512];   // 56 KB
    __shared__ unsigned short Ylds[16][136];        // 4.25 KB, skewed
    __shared__ float sqp[7][16];
    __shared__ float rinvl[16];
    __shared__ float dl[16];

    int tid = threadIdx.x;
    int w = tid >> 6;                 // wave 0..7
    int lane = tid & 63;
    int nrow = lane & 15;
    int quad = lane >> 4;
    int mtile = blockIdx.x;           // rows [16*mtile, +16)

    if (tid < 16) dl[tid] = Dm[(size_t)(mtile * 16 + tid) * (BSZ + 1)];
    __syncthreads();

    f32x4 acc = (f32x4){0.f, 0.f, 0.f, 0.f};

    auto STAGE = [&](int s, int buf) {
        int k0 = 2 * s;
        if (w == 7) {
            #pragma unroll
            for (int j = 0; j < 2; ++j)
                glds16(Asw + (((size_t)mtile * 128 + k0 + j) * 64 + lane) * 8,
                       &Abuf[buf][j][0]);
        } else {
            #pragma unroll
            for (int j = 0; j < 2; ++j)
                glds16(Bsw + (((size_t)(k0 + j) * 7 + w) * 64 + lane) * 8,
                       &Bbuf[buf][j][w][0]);
        }
    };
    auto COMP = [&](int cur) {
        if (w < 7) {
            #pragma unroll
            for (int j = 0; j < 2; ++j) {
                bf16x8 aF = *(bf16x8*)&Abuf[cur][j][lane * 8];
                bf16x8 bF = *(bf16x8*)&Bbuf[cur][j][w][lane * 8];
                acc = __builtin_amdgcn_mfma_f32_16x16x32_bf16(aF, bF, acc, 0, 0, 0);
            }
        }
    };

    STAGE(0, 0); STAGE(1, 1); STAGE(2, 2);
    #pragma unroll 1
    for (int s = 0; s < 61; ++s) {
        asm volatile("s_waitcnt vmcnt(4)" ::: "memory");  // retire stage s's 2 loads
        __builtin_amdgcn_s_barrier();
        STAGE(s + 3, (s + 3) & 3);                        // reuse distance 4 > depth 3
        COMP(s & 3);
    }
    asm volatile("s_waitcnt vmcnt(4)" ::: "memory");
    __builtin_amdgcn_s_barrier();
    COMP(1);
    asm volatile("s_waitcnt vmcnt(2)" ::: "memory");
    __builtin_amdgcn_s_barrier();
    COMP(2);
    asm volatile("s_waitcnt vmcnt(0)" ::: "memory");
    __builtin_amdgcn_s_barrier();
    COMP(3);

    // ---- epilogue: C/D elem (row = quad*4+reg, col = 16w+nrow) ----
    float vv[4];
    if (w < 7) {
        float sqv[4];
        #pragma unroll
        for (int r = 0; r < 4; ++r) {
            vv[r] = acc[r] * dl[quad * 4 + r];    // Y = D .* (A @ T)
            sqv[r] = vv[r] * vv[r];
        }
        #pragma unroll
        for (int off = 1; off < 16; off <<= 1) {  // sum over this wave's 16 cols
            #pragma unroll
            for (int r = 0; r < 4; ++r) sqv[r] += __shfl_xor(sqv[r], off, 64);
        }
        if ((lane & 15) == 0) {
            #pragma unroll
            for (int r = 0; r < 4; ++r) sqp[w][quad * 4 + r] = sqv[r];
        }
    }
    __syncthreads();
    if (tid < 16) {
        float t = 0.f;
        #pragma unroll
        for (int u = 0; u < 7; ++u) t += sqp[u][tid];
        rinvl[tid] = 1.f / fmaxf(sqrtf(t), 1e-12f);
    }
    __syncthreads();
    if (w < 7) {
        #pragma unroll
        for (int r = 0; r < 4; ++r) {
            int row = quad * 4 + r;
            int col = 16 * w + nrow;
            float y = vv[r];
            float nv = y * rinvl[row];
            size_t o = (size_t)(mtile * 16 + row) * EDIM + col;
            if (LAST) {
                out[o] = (accb[o] + nv) * 0.25f;
            } else {
                accb[o] += nv;
                Ylds[row][col] = (unsigned short)f2bf(y);  // un-normalized Y
            }
        }
    }
    if (!LAST) {
        if (w == 7) {   // zero K-pad cols 112..127
            int row = lane >> 2;
            int c0 = 112 + (lane & 3) * 4;
            *(uint2*)&Ylds[row][c0] = make_uint2(0u, 0u);
        }
        __syncthreads();
        // ---- T' = Y @ W^T: wave t (<7) does W-tile t (4 MFMA) ----
        if (w < 7) {
            int t = w;
            bf16x8 aF2[4];
            #pragma unroll
            for (int k = 0; k < 4; ++k)
                aF2[k] = *(bf16x8*)&Ylds[nrow][k * 32 + quad * 8];
            f32x4 c = (f32x4){0.f, 0.f, 0.f, 0.f};
            const float* wr = W + (size_t)(16 * t + nrow) * EDIM;
            #pragma unroll
            for (int k = 0; k < 4; ++k) {
                bf16x8 bW = ldcvt(wr + k * 32 + quad * 8, (k < 3) || (quad < 2));
                c = __builtin_amdgcn_mfma_f32_16x16x32_bf16(aF2[k], bW, c, 0, 0, 0);
            }
            int j0 = mtile * 16;
            int k32f = j0 >> 5;
            int qp = ((j0 >> 4) & 1) * 2 + (quad >> 1);
            int e0 = (quad & 1) * 4;
            uint2 ck;
            ck.x = pack2(c[0], c[1]);
            ck.y = pack2(c[2], c[3]);
            *(uint2*)(BswOut + ((size_t)(k32f * 7 + t) * 64 + qp * 16 + nrow) * 8 + e0) = ck;
        }
    }
}

extern "C" void kernel_launch(void* const* d_in, const int* in_sizes, int n_in,
                              void* d_out, int out_size, void* d_ws, size_t ws_size,
                              hipStream_t stream) {
    (void)in_sizes; (void)n_in; (void)out_size; (void)ws_size;
    const float* emb   = (const float*)d_in[0];
    const float* Dm    = (const float*)d_in[1];
    const float* A     = (const float*)d_in[2];
    const float* slen  = (const float*)d_in[3];
    const float* Ws    = (const float*)d_in[4];
    const int*   items = (const int*)d_in[5];
    float* out = (float*)d_out;

    // workspace layout (16B-aligned), ~61.4 MB total
    char* w = (char*)d_ws;
    float* Sa   = (float*)w;                                      // 1835008 B
    float* accb = Sa + BSZ * EDIM;                                // 1835008 B
    unsigned short* Bsw0 = (unsigned short*)(accb + BSZ * EDIM);  // 917504 B
    unsigned short* Bsw1 = Bsw0 + (size_t)128 * 7 * 64 * 8;       // 917504 B
    unsigned short* Ebf  = Bsw1 + (size_t)128 * 7 * 64 * 8;       // 22400224 B
    unsigned short* Asw  = Ebf + (size_t)100001 * EDIM;           // 33554432 B

    // 1. table -> bf16 + A -> bf16 fragments (one combined stream kernel)
    prep<<<13661, 256, 0, stream>>>(emb, Ebf, A, Asw);
    // 2. gather + mean-pool -> S, acc
    gather_pool_bf<<<BSZ, 256, 0, stream>>>(Ebf, items, slen, Sa, accb);
    // 3. T1 = S @ W0^T
    fused_mid0<<<256, 64, 0, stream>>>(Sa, Ws, Bsw0);
    // 4-6. three fused whole-layer kernels (last writes out)
    bg_layer<0><<<256, 512, 0, stream>>>(Asw, Bsw0, Dm, accb,
                                         Ws + (size_t)EDIM * EDIM, Bsw1, nullptr);
    bg_layer<0><<<256, 512, 0, stream>>>(Asw, Bsw1, Dm, accb,
                                         Ws + (size_t)2 * EDIM * EDIM, Bsw0, nullptr);
    bg_layer<1><<<256, 512, 0, stream>>>(Asw, Bsw0, Dm, accb,
                                         nullptr, nullptr, out);
}

// Round 6
// 274.333 us; speedup vs baseline: 1.1684x; 1.1684x over previous
//
#include <hip/hip_runtime.h>
#include <hip/hip_bf16.h>

#define BSZ 4096
#define MAXLEN 200
#define EDIM 112
#define NPL 8   // K-split partial planes (one per kq block)

typedef __attribute__((ext_vector_type(8))) short bf16x8;
typedef __attribute__((ext_vector_type(4))) float f32x4;

// f32 -> bf16 (RNE), bit-level
static __device__ __forceinline__ short f2bf(float f) {
    unsigned u = __float_as_uint(f);
    unsigned r = (u + 0x7fffu + ((u >> 16) & 1u)) >> 16;
    return (short)r;
}
static __device__ __forceinline__ float bf2f(short s) {
    return __uint_as_float(((unsigned)(unsigned short)s) << 16);
}
static __device__ __forceinline__ bf16x8 cvt8(float4 a, float4 b) {
    bf16x8 r;
    r[0] = f2bf(a.x); r[1] = f2bf(a.y); r[2] = f2bf(a.z); r[3] = f2bf(a.w);
    r[4] = f2bf(b.x); r[5] = f2bf(b.y); r[6] = f2bf(b.z); r[7] = f2bf(b.w);
    return r;
}
static __device__ __forceinline__ unsigned pack2(float a, float b) {
    return ((unsigned)f2bf(a) & 0xffffu) | ((unsigned)f2bf(b) << 16);
}

// async global->LDS, 16 B per lane: global src per-lane, LDS dest uniform+lane*16.
static __device__ __forceinline__ void glds16(const unsigned short* g, unsigned short* l) {
    __builtin_amdgcn_global_load_lds(
        (__attribute__((address_space(1))) void*)(void*)g,
        (__attribute__((address_space(3))) void*)l, 16, 0, 0);
}

// Streaming f32 -> bf16; first `zgroups` 8-elem groups are zeros (PAD row).
__global__ __launch_bounds__(256) void f32_to_bf16(const float* __restrict__ src,
                                                   unsigned short* __restrict__ dst,
                                                   int ngroups, int zgroups) {
    int g = blockIdx.x * 256 + threadIdx.x;
    if (g >= ngroups) return;
    bf16x8 o;
    if (g < zgroups) {
        #pragma unroll
        for (int i = 0; i < 8; ++i) o[i] = 0;
    } else {
        const float* p = src + (size_t)(g - zgroups) * 8;
        float4 a = *(const float4*)p;
        float4 b = *(const float4*)(p + 4);
        o = cvt8(a, b);
    }
    *(bf16x8*)(dst + (size_t)g * 8) = o;
}

// bf16-table gather+mean-pool. One block per session; 4 waves x 4 rows/wave,
// 16 B/lane loads; Ebf row 0 is zeros (PAD).  Writes S and inits acc.
__global__ __launch_bounds__(256) void gather_pool_bf(const unsigned short* __restrict__ Ebf,
                                                      const int* __restrict__ items,
                                                      const float* __restrict__ slen,
                                                      float* __restrict__ S,
                                                      float* __restrict__ acc) {
    __shared__ float part[16][14][8];
    int wave = threadIdx.x >> 6;
    int lane = threadIdx.x & 63;
    int b = blockIdx.x;
    int rg = lane / 14;   // 0..3 for lanes 0..55
    int c  = lane % 14;
    const int* it = items + (size_t)b * MAXLEN + wave * 50;
    float a[8];
    #pragma unroll
    for (int e = 0; e < 8; ++e) a[e] = 0.f;
    if (lane < 56) {
        #pragma unroll
        for (int t = 0; t < 13; ++t) {
            int j = t * 4 + rg;
            int idx = 0;
            if (j < 50) idx = it[j];               // idx==0 -> zero row (PAD)
            bf16x8 v = *(const bf16x8*)(Ebf + (size_t)idx * EDIM + c * 8);
            #pragma unroll
            for (int e = 0; e < 8; ++e) a[e] += bf2f(v[e]);
        }
        #pragma unroll
        for (int e = 0; e < 8; ++e) part[wave * 4 + rg][c][e] = a[e];
    }
    __syncthreads();
    int tid = threadIdx.x;
    if (tid < EDIM) {
        int cc = tid >> 3, ee = tid & 7;
        float s = 0.f;
        #pragma unroll
        for (int g = 0; g < 16; ++g) s += part[g][cc][ee];
        s /= slen[b];
        S[(size_t)b * EDIM + tid]   = s;
        acc[(size_t)b * EDIM + tid] = s;
    }
}

// Load 8 consecutive f32 (if valid) -> bf16x8 fragment.
static __device__ __forceinline__ bf16x8 ldcvt(const float* p, bool valid) {
    if (valid) {
        float4 a = *(const float4*)(p);
        float4 b = *(const float4*)(p + 4);
        return cvt8(a, b);
    }
    bf16x8 z;
    #pragma unroll
    for (int i = 0; i < 8; ++i) z[i] = 0;
    return z;
}

// Layer-0 only: T1 = S @ W0^T -> Bsw fragment layout.  One wave per 16
// sessions, grid 256.
__global__ __launch_bounds__(64, 4) void fused_mid0(const float* __restrict__ Sin,
                                                    const float* __restrict__ W,
                                                    unsigned short* __restrict__ Bsw) {
    __shared__ unsigned short Ylds[16][136];  // bank-skewed rows
    int lane = threadIdx.x;
    int gw = blockIdx.x;          // 0..255
    int j0 = gw * 16;
    int nrow = lane & 15;
    int quad = lane >> 4;
    int ses = j0 + nrow;

    float4 v[7];
    const float4* p = (const float4*)(Sin + (size_t)ses * EDIM + quad * 28);
    #pragma unroll
    for (int i = 0; i < 7; ++i) v[i] = p[i];

    #pragma unroll
    for (int i = 0; i < 7; ++i) {
        uint2 pk;
        pk.x = pack2(v[i].x, v[i].y);
        pk.y = pack2(v[i].z, v[i].w);
        *(uint2*)&Ylds[nrow][quad * 28 + i * 4] = pk;
    }
    *(uint2*)&Ylds[nrow][112 + quad * 4] = make_uint2(0u, 0u);
    __syncthreads();

    bf16x8 aF[4];
    #pragma unroll
    for (int k32 = 0; k32 < 4; ++k32)
        aF[k32] = *(bf16x8*)&Ylds[nrow][k32 * 32 + quad * 8];

    f32x4 acc[7];
    #pragma unroll
    for (int t = 0; t < 7; ++t) acc[t] = (f32x4){0.f, 0.f, 0.f, 0.f};
    #pragma unroll
    for (int t = 0; t < 7; ++t) {
        const float* wr = W + (size_t)(16 * t + nrow) * EDIM;
        #pragma unroll
        for (int k32 = 0; k32 < 4; ++k32) {
            bf16x8 bF = ldcvt(wr + k32 * 32 + quad * 8, (k32 < 3) || (quad < 2));
            acc[t] = __builtin_amdgcn_mfma_f32_16x16x32_bf16(aF[k32], bF, acc[t], 0, 0, 0);
        }
    }

    int k32f = j0 >> 5;
    int qp = ((j0 >> 4) & 1) * 2 + (quad >> 1);
    int e0 = (quad & 1) * 4;
    #pragma unroll
    for (int t = 0; t < 7; ++t) {
        uint2 pk;
        pk.x = pack2(acc[t][0], acc[t][1]);
        pk.y = pack2(acc[t][2], acc[t][3]);
        *(uint2*)(Bsw + ((size_t)(k32f * 7 + t) * 64 + qp * 16 + nrow) * 8 + e0) = pk;
    }
}

// K-split GEMM, B-in-LDS, A-in-regs: grid 256 = 32 M-tiles(128 rows) x 8
// K-chunks (K=512), 8 waves x 512 thr, 1 block/CU.
// The block's B-slice (16 k32 x 7 frags = 56 KB) is staged into a 28-KB LDS
// buffer in TWO phases (wave w stages its k32 slice; 3 barriers total).
// Each wave prefetches ALL 16 of its A-fragments into registers up front
// (64 VGPR, statically indexed).  The compute loop has ZERO global loads and
// ZERO barriers: 112 MFMA + 112 conflict-free ds_read_b128, waves free-run.
// acc -> partial plane kq (no cross-wave reduce; waves own disjoint rows).
// AMODE 0: A read as f32, cvt in-register, side-write Asw.  AMODE 1: read Asw.
template <int AMODE>
__global__ __launch_bounds__(512, 2) void bg_ks(const float* __restrict__ Af,
                                                unsigned short* __restrict__ Asw,
                                                const unsigned short* __restrict__ Bsw,
                                                float* __restrict__ Yp) {
    __shared__ unsigned short Bl[8 * 7 * 512];   // 28 KB (one phase: 8 k32 x 7)
    int tid = threadIdx.x;
    int w = tid >> 6;                 // 0..7 (= sub-mtile owned by this wave)
    int lane = tid & 63;
    int nrow = lane & 15;
    int quad = lane >> 4;
    int mtile = blockIdx.x & 31;      // 128-row tile
    int kq = blockIdx.x >> 5;         // 0..7
    int M16 = mtile * 8 + w;          // 16-row tile index, 0..255
    int k32b = kq * 16;

    // ---- phase-0 B staging: wave w stages local k32 = w (7 frags) ----
    #pragma unroll
    for (int t = 0; t < 7; ++t)
        glds16(Bsw + (((size_t)(k32b + w) * 7 + t) * 64 + lane) * 8,
               &Bl[(w * 7 + t) * 512]);

    // ---- prefetch ALL 16 A-frags into regs (static indices) ----
    bf16x8 aF[16];
    if (AMODE == 0) {
        #pragma unroll
        for (int k = 0; k < 16; ++k) {
            const float* p = Af + (size_t)(M16 * 16 + nrow) * BSZ
                             + (k32b + k) * 32 + quad * 8;
            float4 a0 = *(const float4*)p;
            float4 a1 = *(const float4*)(p + 4);
            aF[k] = cvt8(a0, a1);
            *(bf16x8*)(Asw + (((size_t)M16 * 128 + k32b + k) * 64 + lane) * 8) = aF[k];
        }
    } else {
        #pragma unroll
        for (int k = 0; k < 16; ++k)
            aF[k] = *(const bf16x8*)(Asw + (((size_t)M16 * 128 + k32b + k) * 64 + lane) * 8);
    }

    f32x4 acc[7];
    #pragma unroll
    for (int t = 0; t < 7; ++t) acc[t] = (f32x4){0.f, 0.f, 0.f, 0.f};

    asm volatile("s_waitcnt vmcnt(0)" ::: "memory");
    __syncthreads();

    // ---- compute phase 0: k = 0..7, no barriers, no global loads ----
    #pragma unroll
    for (int k = 0; k < 8; ++k)
        #pragma unroll
        for (int t = 0; t < 7; ++t) {
            bf16x8 bF = *(bf16x8*)&Bl[(k * 7 + t) * 512 + lane * 8];
            acc[t] = __builtin_amdgcn_mfma_f32_16x16x32_bf16(aF[k], bF, acc[t], 0, 0, 0);
        }

    // ---- phase-1 B staging into the same buffer (WAR-safe: barrier both sides)
    __syncthreads();
    #pragma unroll
    for (int t = 0; t < 7; ++t)
        glds16(Bsw + (((size_t)(k32b + 8 + w) * 7 + t) * 64 + lane) * 8,
               &Bl[(w * 7 + t) * 512]);
    asm volatile("s_waitcnt vmcnt(0)" ::: "memory");
    __syncthreads();

    // ---- compute phase 1: k = 8..15 ----
    #pragma unroll
    for (int k = 0; k < 8; ++k)
        #pragma unroll
        for (int t = 0; t < 7; ++t) {
            bf16x8 bF = *(bf16x8*)&Bl[(k * 7 + t) * 512 + lane * 8];
            acc[t] = __builtin_amdgcn_mfma_f32_16x16x32_bf16(aF[8 + k], bF, acc[t], 0, 0, 0);
        }

    // ---- C/D: (m = quad*4 + r, n = 16t + nrow) -> partial plane kq ----
    float* dst = Yp + (size_t)kq * BSZ * EDIM + (size_t)M16 * 16 * EDIM;
    #pragma unroll
    for (int t = 0; t < 7; ++t)
        #pragma unroll
        for (int r = 0; r < 4; ++r)
            dst[(size_t)(quad * 4 + r) * EDIM + 16 * t + nrow] = acc[t][r];
}

// Per-layer epilogue: sum NPL partials, d-scale, acc += Y/||Y||, and
// T' = Y @ W^T -> Bsw fragments.  One wave per 16 sessions, grid 256.
__global__ __launch_bounds__(64, 4) void epi_mid(const float* __restrict__ Yp,
                                                 const float* __restrict__ Dm,
                                                 float* __restrict__ accb,
                                                 const float* __restrict__ W,
                                                 unsigned short* __restrict__ Bsw) {
    __shared__ unsigned short Ylds[16][136];
    int lane = threadIdx.x;
    int gw = blockIdx.x;
    int j0 = gw * 16;
    int nrow = lane & 15;
    int quad = lane >> 4;
    int ses = j0 + nrow;

    float4 v[7];
    #pragma unroll
    for (int i = 0; i < 7; ++i) v[i] = make_float4(0.f, 0.f, 0.f, 0.f);
    #pragma unroll
    for (int pp = 0; pp < NPL; ++pp) {
        const float4* p = (const float4*)(Yp + (size_t)pp * BSZ * EDIM
                                          + (size_t)ses * EDIM + quad * 28);
        #pragma unroll
        for (int i = 0; i < 7; ++i) {
            float4 t = p[i];
            v[i].x += t.x; v[i].y += t.y; v[i].z += t.z; v[i].w += t.w;
        }
    }
    float d = Dm[(size_t)ses * (BSZ + 1)];
    float ss = 0.f;
    #pragma unroll
    for (int i = 0; i < 7; ++i) {
        v[i].x *= d; v[i].y *= d; v[i].z *= d; v[i].w *= d;
        ss += v[i].x * v[i].x + v[i].y * v[i].y + v[i].z * v[i].z + v[i].w * v[i].w;
    }
    ss += __shfl_xor(ss, 16, 64);
    ss += __shfl_xor(ss, 32, 64);
    float rinv = 1.f / fmaxf(sqrtf(ss), 1e-12f);
    float4* pa = (float4*)(accb + (size_t)ses * EDIM + quad * 28);
    #pragma unroll
    for (int i = 0; i < 7; ++i) {
        float4 a = pa[i];
        a.x += v[i].x * rinv; a.y += v[i].y * rinv;
        a.z += v[i].z * rinv; a.w += v[i].w * rinv;
        pa[i] = a;
    }

    // bf16 Y tile to LDS (cols 112..127 zeroed for K-padding)
    #pragma unroll
    for (int i = 0; i < 7; ++i) {
        uint2 pk;
        pk.x = pack2(v[i].x, v[i].y);
        pk.y = pack2(v[i].z, v[i].w);
        *(uint2*)&Ylds[nrow][quad * 28 + i * 4] = pk;
    }
    *(uint2*)&Ylds[nrow][112 + quad * 4] = make_uint2(0u, 0u);
    __syncthreads();

    bf16x8 aF[4];
    #pragma unroll
    for (int k32 = 0; k32 < 4; ++k32)
        aF[k32] = *(bf16x8*)&Ylds[nrow][k32 * 32 + quad * 8];

    f32x4 acc[7];
    #pragma unroll
    for (int t = 0; t < 7; ++t) acc[t] = (f32x4){0.f, 0.f, 0.f, 0.f};
    #pragma unroll
    for (int t = 0; t < 7; ++t) {
        const float* wr = W + (size_t)(16 * t + nrow) * EDIM;
        #pragma unroll
        for (int k32 = 0; k32 < 4; ++k32) {
            bf16x8 bF = ldcvt(wr + k32 * 32 + quad * 8, (k32 < 3) || (quad < 2));
            acc[t] = __builtin_amdgcn_mfma_f32_16x16x32_bf16(aF[k32], bF, acc[t], 0, 0, 0);
        }
    }

    int k32f = j0 >> 5;
    int qp = ((j0 >> 4) & 1) * 2 + (quad >> 1);
    int e0 = (quad & 1) * 4;
    #pragma unroll
    for (int t = 0; t < 7; ++t) {
        uint2 pk;
        pk.x = pack2(acc[t][0], acc[t][1]);
        pk.y = pack2(acc[t][2], acc[t][3]);
        *(uint2*)(Bsw + ((size_t)(k32f * 7 + t) * 64 + qp * 16 + nrow) * 8 + e0) = pk;
    }
}

// Final: sum NPL partials, d-scale, normalize, out = (acc + nv) / 4.
__global__ __launch_bounds__(256) void final_epilogue(const float* __restrict__ Yp,
                                                      const float* __restrict__ Dm,
                                                      const float* __restrict__ accb,
                                                      float* __restrict__ out) {
    int wave = threadIdx.x >> 6;
    int lane = threadIdx.x & 63;
    int b = blockIdx.x * 4 + wave;

    float2 v = make_float2(0.f, 0.f);
    size_t o2 = (size_t)b * 56 + lane;
    if (lane < 56) {
        #pragma unroll
        for (int p = 0; p < NPL; ++p) {
            float2 t = ((const float2*)(Yp + (size_t)p * BSZ * EDIM))[o2];
            v.x += t.x;
            v.y += t.y;
        }
    }
    float d = Dm[(size_t)b * (BSZ + 1)];
    v.x *= d; v.y *= d;
    float ss = v.x * v.x + v.y * v.y;
    #pragma unroll
    for (int off = 32; off; off >>= 1) ss += __shfl_xor(ss, off, 64);
    float nrm = fmaxf(sqrtf(ss), 1e-12f);
    if (lane < 56) {
        float2 a = ((const float2*)accb)[o2];
        ((float2*)out)[o2] = make_float2((a.x + v.x / nrm) * 0.25f,
                                         (a.y + v.y / nrm) * 0.25f);
    }
}

extern "C" void kernel_launch(void* const* d_in, const int* in_sizes, int n_in,
                              void* d_out, int out_size, void* d_ws, size_t ws_size,
                              hipStream_t stream) {
    (void)in_sizes; (void)n_in; (void)out_size; (void)ws_size;
    const float* emb   = (const float*)d_in[0];
    const float* Dm    = (const float*)d_in[1];
    const float* A     = (const float*)d_in[2];
    const float* slen  = (const float*)d_in[3];
    const float* Ws    = (const float*)d_in[4];
    const int*   items = (const int*)d_in[5];
    float* out = (float*)d_out;

    // workspace layout (16B-aligned), ~73 MB total
    char* w = (char*)d_ws;
    float* Sa   = (float*)w;                                      // 1835008 B
    float* accb = Sa + BSZ * EDIM;                                // 1835008 B
    float* Yp   = accb + BSZ * EDIM;                              // NPL x 1835008 B
    unsigned short* Bsw0 = (unsigned short*)(Yp + (size_t)NPL * BSZ * EDIM); // 917504 B
    unsigned short* Bsw1 = Bsw0 + (size_t)128 * 7 * 64 * 8;       // 917504 B
    unsigned short* Ebf  = Bsw1 + (size_t)128 * 7 * 64 * 8;       // 22400224 B
    unsigned short* Asw  = Ebf + (size_t)100001 * EDIM;           // 33554432 B

    // 1. embedding table -> bf16 (zero PAD row prepended)
    f32_to_bf16<<<5470, 256, 0, stream>>>(emb, Ebf, 1400014, 14);
    // 2. gather + mean-pool -> S, acc
    gather_pool_bf<<<BSZ, 256, 0, stream>>>(Ebf, items, slen, Sa, accb);
    // 3. T1 = S @ W0^T
    fused_mid0<<<256, 64, 0, stream>>>(Sa, Ws, Bsw0);
    // 4-9. three layers: B-in-LDS K-split GEMM + epilogue
    bg_ks<0><<<256, 512, 0, stream>>>(A, Asw, Bsw0, Yp);
    epi_mid<<<256, 64, 0, stream>>>(Yp, Dm, accb, Ws + (size_t)EDIM * EDIM, Bsw1);
    bg_ks<1><<<256, 512, 0, stream>>>(nullptr, Asw, Bsw1, Yp);
    epi_mid<<<256, 64, 0, stream>>>(Yp, Dm, accb, Ws + (size_t)2 * EDIM * EDIM, Bsw0);
    bg_ks<1><<<256, 512, 0, stream>>>(nullptr, Asw, Bsw0, Yp);
    final_epilogue<<<BSZ / 4, 256, 0, stream>>>(Yp, Dm, accb, out);
}